// Round 4
// baseline (209.510 us; speedup 1.0000x reference)
//
#include <hip/hip_runtime.h>

typedef __bf16 bf16;
typedef __attribute__((ext_vector_type(4))) __bf16 bf16x4;
typedef __attribute__((ext_vector_type(8))) __bf16 bf16x8;
typedef __attribute__((ext_vector_type(4))) float f32x4;

#define MFMA16(a, b, c) __builtin_amdgcn_mfma_f32_16x16x32_bf16((a), (b), (c), 0, 0, 0)

// ---------------------------------------------------------------------------
// Kernel 1: W [o][c] fp32 -> hi/lo bf16 split, same [o][c] layout.
// ---------------------------------------------------------------------------
__global__ __launch_bounds__(256) void prep_w_kernel(const float* __restrict__ Wq,
                                                     const float* __restrict__ Wk,
                                                     const int* __restrict__ flag,
                                                     bf16* __restrict__ Wbh,
                                                     bf16* __restrict__ Wbl) {
  const int z = blockIdx.y;
  const float* src = (z == 0) ? Wq : ((flag[0] != 0) ? Wq : Wk);
  int i = (blockIdx.x * 256 + threadIdx.x) * 4;  // 0..16383
  float4 v = *(const float4*)(src + i);
  bf16x4 hi, lo;
  hi[0] = (bf16)v.x; lo[0] = (bf16)(v.x - (float)hi[0]);
  hi[1] = (bf16)v.y; lo[1] = (bf16)(v.y - (float)hi[1]);
  hi[2] = (bf16)v.z; lo[2] = (bf16)(v.z - (float)hi[2]);
  hi[3] = (bf16)v.w; lo[3] = (bf16)(v.w - (float)hi[3]);
  *(bf16x4*)(Wbh + z * 16384 + i) = hi;
  *(bf16x4*)(Wbl + z * 16384 + i) = lo;
}

// ---------------------------------------------------------------------------
// Kernel 1b: V convert, kf fp32 [b][c][q] -> Vb bf16 (same layout).
// ---------------------------------------------------------------------------
__global__ __launch_bounds__(256) void vconv_kernel(const float* __restrict__ kf,
                                                    bf16* __restrict__ Vb) {
  int i = (blockIdx.x * 256 + threadIdx.x) * 8;
  float4 f0 = *(const float4*)(kf + i);
  float4 f1 = *(const float4*)(kf + i + 4);
  bf16x8 v;
  v[0] = (bf16)f0.x; v[1] = (bf16)f0.y; v[2] = (bf16)f0.z; v[3] = (bf16)f0.w;
  v[4] = (bf16)f1.x; v[5] = (bf16)f1.y; v[6] = (bf16)f1.z; v[7] = (bf16)f1.w;
  *(bf16x8*)(Vb + i) = v;
}

// ---------------------------------------------------------------------------
// Kernel 2: MFMA projection. out[b][p][o] = sum_c x[b][c][p] * W[o][c] + bias.
// ---------------------------------------------------------------------------
__global__ __launch_bounds__(256) void proj_kernel(const float* __restrict__ qf,
                                                   const float* __restrict__ kf,
                                                   const bf16* __restrict__ Wbh,
                                                   const bf16* __restrict__ Wbl,
                                                   const float* __restrict__ bq,
                                                   const float* __restrict__ bk,
                                                   const int* __restrict__ flag,
                                                   bf16* __restrict__ Qp,
                                                   bf16* __restrict__ Kp) {
  const int b = blockIdx.y, z = blockIdx.z;
  const float* x = z ? kf : qf;
  const bf16* Wh = Wbh + z * 16384;
  const bf16* Wl = Wbl + z * 16384;
  const float* bias = z ? (flag[0] ? bq : bk) : bq;
  bf16* dst = z ? Kp : Qp;

  const int t = threadIdx.x;
  const int w = t >> 6, lane = t & 63;
  const int g = lane >> 4, l16 = lane & 15;
  const int wo = w >> 1, wp = w & 1;
  const int o0 = wo << 5;
  const int pbase = (blockIdx.x << 7) + (wp << 6);

  f32x4 acc[2][4];
#pragma unroll
  for (int ot = 0; ot < 2; ++ot) {
    float4 bv = *(const float4*)(bias + o0 + (ot << 4) + (g << 2));
#pragma unroll
    for (int pt = 0; pt < 4; ++pt) acc[ot][pt] = (f32x4){bv.x, bv.y, bv.z, bv.w};
  }

  const float* xb = x + ((((b << 8) + (g << 3)) << 10) + pbase + l16);
  const bf16* whb = Wh + ((o0 + l16) << 8) + (g << 3);
  const bf16* wlb = Wl + ((o0 + l16) << 8) + (g << 3);

  for (int kk = 0; kk < 8; ++kk) {
    bf16x8 ah[2], al[2];
#pragma unroll
    for (int ot = 0; ot < 2; ++ot) {
      ah[ot] = *(const bf16x8*)(whb + (ot << 12) + (kk << 5));
      al[ot] = *(const bf16x8*)(wlb + (ot << 12) + (kk << 5));
    }
    const float* xk = xb + (kk << 15);
#pragma unroll
    for (int pt = 0; pt < 4; ++pt) {
      float xv[8];
#pragma unroll
      for (int j = 0; j < 8; ++j) xv[j] = xk[(j << 10) + (pt << 4)];
      bf16x8 xf;
#pragma unroll
      for (int j = 0; j < 8; ++j) xf[j] = (bf16)xv[j];
#pragma unroll
      for (int ot = 0; ot < 2; ++ot) {
        acc[ot][pt] = MFMA16(ah[ot], xf, acc[ot][pt]);
        acc[ot][pt] = MFMA16(al[ot], xf, acc[ot][pt]);
      }
    }
  }

#pragma unroll
  for (int ot = 0; ot < 2; ++ot)
#pragma unroll
    for (int pt = 0; pt < 4; ++pt) {
      bf16x4 q4;
#pragma unroll
      for (int r = 0; r < 4; ++r) q4[r] = (bf16)acc[ot][pt][r];
      int p = pbase + (pt << 4) + l16;
      *(bf16x4*)(dst + (((b << 10) + p) << 6) + o0 + (ot << 4) + (g << 2)) = q4;
    }
}

// ---------------------------------------------------------------------------
// Kernel 3: fused flash attention — ZERO LDS, ZERO barriers.
// grid (32 = 16 p-tiles x 2 ch-halves, 32 batches) x 256 thr (4 indep waves).
// Each wave owns 16 p-rows end-to-end: swapped QK^T (A=K permuted rows, B=Q)
// puts a full P-row in each lane (col=l16); permutation makes the lane's
// 16 P values exactly its PV B-fragment. K/V fragments read direct from
// global (L1/L2-resident). Softmax: in-lane tree + 2 shfls.
// ---------------------------------------------------------------------------
__global__ __launch_bounds__(256) void attn_kernel(const bf16* __restrict__ Vb,
                                                   const bf16* __restrict__ Qp,
                                                   const bf16* __restrict__ Kp,
                                                   float* __restrict__ out) {
  const int b = blockIdx.y;
  const int ptile = blockIdx.x >> 1;
  const int c0 = (blockIdx.x & 1) << 7;  // this block's 128-channel half
  const int p0 = ptile << 6;
  const int t = threadIdx.x;
  const int w = t >> 6, lane = t & 63;
  const int g = lane >> 4, l16 = lane & 15;
  const int p = p0 + (w << 4) + l16;  // this lane's output pixel (D col)

  // Q B-fragments: col=p(=l16), k = o = 8g+j (+32)
  const bf16* qb = Qp + (((b << 10) + p) << 6) + (g << 3);
  const bf16x8 qa0 = *(const bf16x8*)qb;
  const bf16x8 qa1 = *(const bf16x8*)(qb + 32);

  // K A-frag row permutation: mfma #qt, frag-row l16 reads K row
  //   qbase + 4*(qt&1) + 32*(qt>>1),  qbase = 8*(l16>>2) + (l16&3)
  // => D-row (4g+r of mfma qt) holds q = 8g + 4(qt&1) + r + 32(qt>>1),
  //    i.e. lane's s[qt][r] are exactly P[p][8g+j] / P[p][32+8g+j].
  const int qbase = ((l16 >> 2) << 3) + (l16 & 3);
  const bf16* kb = Kp + (b << 16) + (qbase << 6) + (g << 3);
  // V A-frags: row c = c0+16ct+l16, k = q = 8g+j (+32)
  const bf16* vb = Vb + (((b << 8) + c0 + l16) << 10) + (g << 3);

  f32x4 acc[8];  // D[c][p]: rows c = c0+16ct+4g+r, col p (fixed per lane)
#pragma unroll
  for (int i = 0; i < 8; ++i) acc[i] = (f32x4){0.f, 0.f, 0.f, 0.f};
  float m_ = -1e30f, l_ = 0.f;

  for (int kt = 0; kt < 16; ++kt) {
    // ---- S^T = K·Q^T (8 mfma, K rows permuted) ----
    const bf16* kq = kb + (kt << 12);
    f32x4 s[4];
#pragma unroll
    for (int qt = 0; qt < 4; ++qt) {
      const bf16* ka = kq + ((qt & 1) << 8) + ((qt >> 1) << 11);
      bf16x8 ka0 = *(const bf16x8*)ka;
      bf16x8 ka1 = *(const bf16x8*)(ka + 32);
      f32x4 z = (f32x4){0.f, 0.f, 0.f, 0.f};
      z = MFMA16(ka0, qa0, z);
      s[qt] = MFMA16(ka1, qa1, z);
    }
    // ---- row max: 15 in-lane + 2 shfl ----
    float tm = fmaxf(fmaxf(fmaxf(s[0][0], s[0][1]), fmaxf(s[0][2], s[0][3])),
                     fmaxf(fmaxf(s[1][0], s[1][1]), fmaxf(s[1][2], s[1][3])));
    float tn = fmaxf(fmaxf(fmaxf(s[2][0], s[2][1]), fmaxf(s[2][2], s[2][3])),
                     fmaxf(fmaxf(s[3][0], s[3][1]), fmaxf(s[3][2], s[3][3])));
    tm = fmaxf(tm, tn);
    tm = fmaxf(tm, __shfl_xor(tm, 16));
    tm = fmaxf(tm, __shfl_xor(tm, 32));
    float mn = fmaxf(m_, tm);
    if (mn - m_ <= 8.f) mn = m_;  // defer-max (P bounded by e^8)
    float sc = __expf(m_ - mn);   // exactly 1.0 when deferred
    m_ = mn;
    // ---- exp (in-lane, 16 values) ----
#pragma unroll
    for (int qt = 0; qt < 4; ++qt)
#pragma unroll
      for (int r = 0; r < 4; ++r) s[qt][r] = __expf(s[qt][r] - m_);
    // ---- row sum: 15 in-lane + 2 shfl ----
    float rs = ((s[0][0] + s[0][1]) + (s[0][2] + s[0][3])) +
               ((s[1][0] + s[1][1]) + (s[1][2] + s[1][3])) +
               ((s[2][0] + s[2][1]) + (s[2][2] + s[2][3])) +
               ((s[3][0] + s[3][1]) + (s[3][2] + s[3][3]));
    rs += __shfl_xor(rs, 16);
    rs += __shfl_xor(rs, 32);
    l_ = l_ * sc + rs;
    // ---- conditional acc rescale (skipped when whole wave deferred) ----
    if (__any(sc != 1.f)) {
#pragma unroll
      for (int i = 0; i < 8; ++i) {
        acc[i][0] *= sc; acc[i][1] *= sc; acc[i][2] *= sc; acc[i][3] *= sc;
      }
    }
    // ---- P -> bf16 B-fragments, fully in-lane (permutation payoff) ----
    bf16x8 pb0, pb1;
#pragma unroll
    for (int r = 0; r < 4; ++r) {
      pb0[r] = (bf16)s[0][r];
      pb0[4 + r] = (bf16)s[1][r];
      pb1[r] = (bf16)s[2][r];
      pb1[4 + r] = (bf16)s[3][r];
    }
    // ---- PV: V A-frags direct from global, 16 mfma ----
    const bf16* vq = vb + (kt << 6);
#pragma unroll
    for (int ct = 0; ct < 8; ++ct) {
      const bf16* va = vq + (ct << 14);
      bf16x8 va0 = *(const bf16x8*)va;
      bf16x8 va1 = *(const bf16x8*)(va + 32);
      acc[ct] = MFMA16(va0, pb0, acc[ct]);
      acc[ct] = MFMA16(va1, pb1, acc[ct]);
    }
  }

  // ---- epilogue: per-lane normalize, direct stores (16-lane 64B runs) ----
  const float inv = 1.f / l_;
  float* ob = out + ((size_t)b << 18) + p;
#pragma unroll
  for (int ct = 0; ct < 8; ++ct)
#pragma unroll
    for (int r = 0; r < 4; ++r) {
      int c = c0 + (ct << 4) + (g << 2) + r;
      ob[c << 10] = acc[ct][r] * inv;
    }
}

// ---------------------------------------------------------------------------
extern "C" void kernel_launch(void* const* d_in, const int* in_sizes, int n_in,
                              void* d_out, int out_size, void* d_ws, size_t ws_size,
                              hipStream_t stream) {
  const float* qf = (const float*)d_in[0];
  const float* kf = (const float*)d_in[1];
  const float* Wq = (const float*)d_in[2];
  const float* bq = (const float*)d_in[3];
  const float* Wk = (const float*)d_in[4];
  const float* bk = (const float*)d_in[5];
  // d_in[6] = vis_CA (unused)
  const int* flag = (const int*)d_in[7];  // same_WqWk
  float* out = (float*)d_out;

  char* ws = (char*)d_ws;
  bf16* Qp = (bf16*)ws;                          // 4 MiB: [32][1024][64] bf16
  bf16* Kp = (bf16*)(ws + (4u << 20));           // 4 MiB
  bf16* Wbh = (bf16*)(ws + (8u << 20));          // 64 KiB: [2][64][256] bf16
  bf16* Wbl = (bf16*)(ws + (8u << 20) + 65536);  // 64 KiB
  bf16* Vb = (bf16*)(ws + (9u << 20));           // 16 MiB: [32][256][1024] bf16

  prep_w_kernel<<<dim3(16, 2), 256, 0, stream>>>(Wq, Wk, flag, Wbh, Wbl);
  vconv_kernel<<<4096, 256, 0, stream>>>(kf, Vb);
  proj_kernel<<<dim3(8, 32, 2), 256, 0, stream>>>(qf, kf, Wbh, Wbl, bq, bk, flag, Qp, Kp);
  attn_kernel<<<dim3(32, 32), 256, 0, stream>>>(Vb, Qp, Kp, out);
}

// Round 5
// 73.006 us; speedup vs baseline: 2.8698x; 2.8698x over previous
//
#include <hip/hip_runtime.h>

typedef __bf16 bf16;
typedef __attribute__((ext_vector_type(4))) __bf16 bf16x4;
typedef __attribute__((ext_vector_type(8))) __bf16 bf16x8;
typedef __attribute__((ext_vector_type(4))) float f32x4;

#define MFMA16(a, b, c) __builtin_amdgcn_mfma_f32_16x16x32_bf16((a), (b), (c), 0, 0, 0)

// ---------------------------------------------------------------------------
// Kernel 1: W [o][c] fp32 -> hi/lo bf16 split, same [o][c] layout.
// ---------------------------------------------------------------------------
__global__ __launch_bounds__(256) void prep_w_kernel(const float* __restrict__ Wq,
                                                     const float* __restrict__ Wk,
                                                     const int* __restrict__ flag,
                                                     bf16* __restrict__ Wbh,
                                                     bf16* __restrict__ Wbl) {
  const int z = blockIdx.y;
  const float* src = (z == 0) ? Wq : ((flag[0] != 0) ? Wq : Wk);
  int i = (blockIdx.x * 256 + threadIdx.x) * 4;  // 0..16383
  float4 v = *(const float4*)(src + i);
  bf16x4 hi, lo;
  hi[0] = (bf16)v.x; lo[0] = (bf16)(v.x - (float)hi[0]);
  hi[1] = (bf16)v.y; lo[1] = (bf16)(v.y - (float)hi[1]);
  hi[2] = (bf16)v.z; lo[2] = (bf16)(v.z - (float)hi[2]);
  hi[3] = (bf16)v.w; lo[3] = (bf16)(v.w - (float)hi[3]);
  *(bf16x4*)(Wbh + z * 16384 + i) = hi;
  *(bf16x4*)(Wbl + z * 16384 + i) = lo;
}

// ---------------------------------------------------------------------------
// Kernel 1b: V convert, kf fp32 [b][c][q] -> Vb bf16 (same layout).
// ---------------------------------------------------------------------------
__global__ __launch_bounds__(256) void vconv_kernel(const float* __restrict__ kf,
                                                    bf16* __restrict__ Vb) {
  int i = (blockIdx.x * 256 + threadIdx.x) * 8;
  float4 f0 = *(const float4*)(kf + i);
  float4 f1 = *(const float4*)(kf + i + 4);
  bf16x8 v;
  v[0] = (bf16)f0.x; v[1] = (bf16)f0.y; v[2] = (bf16)f0.z; v[3] = (bf16)f0.w;
  v[4] = (bf16)f1.x; v[5] = (bf16)f1.y; v[6] = (bf16)f1.z; v[7] = (bf16)f1.w;
  *(bf16x8*)(Vb + i) = v;
}

// ---------------------------------------------------------------------------
// Kernel 2: MFMA projection. out[b][p][o] = sum_c x[b][c][p] * W[o][c] + bias.
// ---------------------------------------------------------------------------
__global__ __launch_bounds__(256) void proj_kernel(const float* __restrict__ qf,
                                                   const float* __restrict__ kf,
                                                   const bf16* __restrict__ Wbh,
                                                   const bf16* __restrict__ Wbl,
                                                   const float* __restrict__ bq,
                                                   const float* __restrict__ bk,
                                                   const int* __restrict__ flag,
                                                   bf16* __restrict__ Qp,
                                                   bf16* __restrict__ Kp) {
  const int b = blockIdx.y, z = blockIdx.z;
  const float* x = z ? kf : qf;
  const bf16* Wh = Wbh + z * 16384;
  const bf16* Wl = Wbl + z * 16384;
  const float* bias = z ? (flag[0] ? bq : bk) : bq;
  bf16* dst = z ? Kp : Qp;

  const int t = threadIdx.x;
  const int w = t >> 6, lane = t & 63;
  const int g = lane >> 4, l16 = lane & 15;
  const int wo = w >> 1, wp = w & 1;
  const int o0 = wo << 5;
  const int pbase = (blockIdx.x << 7) + (wp << 6);

  f32x4 acc[2][4];
#pragma unroll
  for (int ot = 0; ot < 2; ++ot) {
    float4 bv = *(const float4*)(bias + o0 + (ot << 4) + (g << 2));
#pragma unroll
    for (int pt = 0; pt < 4; ++pt) acc[ot][pt] = (f32x4){bv.x, bv.y, bv.z, bv.w};
  }

  const float* xb = x + ((((b << 8) + (g << 3)) << 10) + pbase + l16);
  const bf16* whb = Wh + ((o0 + l16) << 8) + (g << 3);
  const bf16* wlb = Wl + ((o0 + l16) << 8) + (g << 3);

  for (int kk = 0; kk < 8; ++kk) {
    bf16x8 ah[2], al[2];
#pragma unroll
    for (int ot = 0; ot < 2; ++ot) {
      ah[ot] = *(const bf16x8*)(whb + (ot << 12) + (kk << 5));
      al[ot] = *(const bf16x8*)(wlb + (ot << 12) + (kk << 5));
    }
    const float* xk = xb + (kk << 15);
#pragma unroll
    for (int pt = 0; pt < 4; ++pt) {
      float xv[8];
#pragma unroll
      for (int j = 0; j < 8; ++j) xv[j] = xk[(j << 10) + (pt << 4)];
      bf16x8 xf;
#pragma unroll
      for (int j = 0; j < 8; ++j) xf[j] = (bf16)xv[j];
#pragma unroll
      for (int ot = 0; ot < 2; ++ot) {
        acc[ot][pt] = MFMA16(ah[ot], xf, acc[ot][pt]);
        acc[ot][pt] = MFMA16(al[ot], xf, acc[ot][pt]);
      }
    }
  }

#pragma unroll
  for (int ot = 0; ot < 2; ++ot)
#pragma unroll
    for (int pt = 0; pt < 4; ++pt) {
      bf16x4 q4;
#pragma unroll
      for (int r = 0; r < 4; ++r) q4[r] = (bf16)acc[ot][pt][r];
      int p = pbase + (pt << 4) + l16;
      *(bf16x4*)(dst + (((b << 10) + p) << 6) + o0 + (ot << 4) + (g << 2)) = q4;
    }
}

// ---------------------------------------------------------------------------
// Kernel 3: fused flash attention — swapped QK^T (P in-lane), LDS-staged K/V
// with T14 issue-early/write-late, bank-floor swizzle blk^(row&7).
// grid (16 p-tiles, 32 batches) x 256 thr (4 waves x 16 p-rows).
// KVBLK=64, 16 iters. K-row permutation R_qt(i)=8(i>>2)+2(i&3)+(qt&1)+32(qt>>1)
// => lane(u,l16) D-elems s[qt][r] = P[p][8u+2r+(qt&1)+32(qt>>1)]
// => pb0[2r+(qt&1)]=s[qt][r] (qt<2), pb1 likewise (qt>=2). Zero P LDS traffic.
// ---------------------------------------------------------------------------
__global__ __launch_bounds__(256) void attn_kernel(const bf16* __restrict__ Vb,
                                                   const bf16* __restrict__ Qp,
                                                   const bf16* __restrict__ Kp,
                                                   float* __restrict__ out) {
  const int b = blockIdx.y;
  const int p0 = blockIdx.x << 6;
  const int t = threadIdx.x;
  const int w = t >> 6, lane = t & 63;
  const int u = lane >> 4, l16 = lane & 15;
  const int p = p0 + (w << 4) + l16;  // this lane's output pixel (D col)

  __shared__ __align__(16) unsigned char sK[8192];   // [64 q][64 o] bf16, swz
  __shared__ __align__(16) unsigned char sV[32768];  // [256 c][64 q] bf16, swz

  // staging decomposition: thread t -> (row sr = t>>3, 16B-block jb = t&7)
  const int sr = t >> 3, jb = t & 7;
  const int st_ds = sr * 128 + 16 * (jb ^ (sr & 7));  // swizzled LDS byte addr
  const bf16* kp_src = Kp + (((b << 10) + sr) << 6) + (jb << 3);
  const bf16* vb_src = Vb + (((b << 8) + sr) << 10) + (jb << 3);

  // Q B-fragments (col=p, k=o=8u+j / 32+8u+j), direct from global once
  const bf16* qb = Qp + (((b << 10) + p) << 6) + (u << 3);
  const bf16x8 qa0 = *(const bf16x8*)qb;
  const bf16x8 qa1 = *(const bf16x8*)(qb + 32);

  // fragment-read LDS offsets
  const int Rb = ((l16 >> 2) << 3) + ((l16 & 3) << 1);  // K perm base
  const int v0off = l16 * 128 + 16 * (u ^ (l16 & 7));
  const int v1off = l16 * 128 + 16 * ((u + 4) ^ (l16 & 7));

  f32x4 acc[16];  // D[c][p]: c = 16ct + 4u + r
#pragma unroll
  for (int i = 0; i < 16; ++i) acc[i] = (f32x4){0.f, 0.f, 0.f, 0.f};
  float m_ = -1e30f, l_ = 0.f;

  // ---- prologue: stage tile 0 ----
  bf16x8 kst0 = *(const bf16x8*)kp_src;
  bf16x8 kst1 = *(const bf16x8*)(kp_src + (32 << 6));
  bf16x8 vst[8];
#pragma unroll
  for (int v = 0; v < 8; ++v) vst[v] = *(const bf16x8*)(vb_src + (v << 15));
  *(bf16x8*)(sK + st_ds) = kst0;
  *(bf16x8*)(sK + st_ds + 4096) = kst1;
#pragma unroll
  for (int v = 0; v < 8; ++v) *(bf16x8*)(sV + st_ds + (v << 12)) = vst[v];
  __syncthreads();

  for (int kt = 0; kt < 16; ++kt) {
    // ---- T14: issue next tile's global loads early (latency under compute) ----
    if (kt < 15) {
      const bf16* kn = kp_src + ((kt + 1) << 12);
      kst0 = *(const bf16x8*)kn;
      kst1 = *(const bf16x8*)(kn + (32 << 6));
      const bf16* vn = vb_src + ((kt + 1) << 6);
#pragma unroll
      for (int v = 0; v < 8; ++v) vst[v] = *(const bf16x8*)(vn + (v << 15));
    }
    // ---- S^T = K·Q^T (8 mfma, permuted K rows from swizzled LDS) ----
    f32x4 s[4];
#pragma unroll
    for (int qt = 0; qt < 4; ++qt) {
      const int R = Rb + (qt & 1) + ((qt >> 1) << 5);
      const int rb = R * 128;
      bf16x8 k0 = *(const bf16x8*)(sK + rb + 16 * (u ^ (R & 7)));
      bf16x8 k1 = *(const bf16x8*)(sK + rb + 16 * ((u + 4) ^ (R & 7)));
      f32x4 z = (f32x4){0.f, 0.f, 0.f, 0.f};
      z = MFMA16(k0, qa0, z);
      s[qt] = MFMA16(k1, qa1, z);
    }
    // ---- softmax: in-lane 16-val reduce + 2 shfl, defer-max THR=8 ----
    float tq0 = fmaxf(fmaxf(s[0][0], s[0][1]), fmaxf(s[0][2], s[0][3]));
    float tq1 = fmaxf(fmaxf(s[1][0], s[1][1]), fmaxf(s[1][2], s[1][3]));
    float tq2 = fmaxf(fmaxf(s[2][0], s[2][1]), fmaxf(s[2][2], s[2][3]));
    float tq3 = fmaxf(fmaxf(s[3][0], s[3][1]), fmaxf(s[3][2], s[3][3]));
    float tm = fmaxf(fmaxf(tq0, tq1), fmaxf(tq2, tq3));
    tm = fmaxf(tm, __shfl_xor(tm, 16));
    tm = fmaxf(tm, __shfl_xor(tm, 32));
    float mn = fmaxf(m_, tm);
    if (mn - m_ <= 8.f) mn = m_;  // defer (P bounded by e^8)
    float sc = __expf(m_ - mn);   // exactly 1.0 when deferred
    m_ = mn;
#pragma unroll
    for (int qt = 0; qt < 4; ++qt)
#pragma unroll
      for (int r = 0; r < 4; ++r) s[qt][r] = __expf(s[qt][r] - m_);
    float rs = ((s[0][0] + s[0][1]) + (s[0][2] + s[0][3])) +
               ((s[1][0] + s[1][1]) + (s[1][2] + s[1][3])) +
               ((s[2][0] + s[2][1]) + (s[2][2] + s[2][3])) +
               ((s[3][0] + s[3][1]) + (s[3][2] + s[3][3]));
    rs += __shfl_xor(rs, 16);
    rs += __shfl_xor(rs, 32);
    l_ = l_ * sc + rs;
    if (__any(sc != 1.f)) {
#pragma unroll
      for (int i = 0; i < 16; ++i) {
        acc[i][0] *= sc; acc[i][1] *= sc; acc[i][2] *= sc; acc[i][3] *= sc;
      }
    }
    // ---- P -> bf16 B-fragments fully in-lane (permutation payoff) ----
    bf16x8 pb0, pb1;
#pragma unroll
    for (int r = 0; r < 4; ++r) {
      pb0[2 * r] = (bf16)s[0][r];
      pb0[2 * r + 1] = (bf16)s[1][r];
      pb1[2 * r] = (bf16)s[2][r];
      pb1[2 * r + 1] = (bf16)s[3][r];
    }
    // ---- PV: 32 mfma, V A-frags from swizzled LDS ----
#pragma unroll
    for (int ct = 0; ct < 16; ++ct) {
      bf16x8 v0 = *(const bf16x8*)(sV + (ct << 11) + v0off);
      bf16x8 v1 = *(const bf16x8*)(sV + (ct << 11) + v1off);
      acc[ct] = MFMA16(v0, pb0, acc[ct]);
      acc[ct] = MFMA16(v1, pb1, acc[ct]);
    }
    __syncthreads();  // all reads of current tile done
    if (kt < 15) {
      *(bf16x8*)(sK + st_ds) = kst0;
      *(bf16x8*)(sK + st_ds + 4096) = kst1;
#pragma unroll
      for (int v = 0; v < 8; ++v) *(bf16x8*)(sV + st_ds + (v << 12)) = vst[v];
      __syncthreads();  // next tile published
    }
  }

  // ---- epilogue: per-lane normalize, direct stores (16-lane 64B runs) ----
  const float inv = 1.f / l_;
  float* ob = out + ((size_t)b << 18) + p;
#pragma unroll
  for (int ct = 0; ct < 16; ++ct)
#pragma unroll
    for (int r = 0; r < 4; ++r) {
      int c = (ct << 4) + (u << 2) + r;
      ob[c << 10] = acc[ct][r] * inv;
    }
}

// ---------------------------------------------------------------------------
extern "C" void kernel_launch(void* const* d_in, const int* in_sizes, int n_in,
                              void* d_out, int out_size, void* d_ws, size_t ws_size,
                              hipStream_t stream) {
  const float* qf = (const float*)d_in[0];
  const float* kf = (const float*)d_in[1];
  const float* Wq = (const float*)d_in[2];
  const float* bq = (const float*)d_in[3];
  const float* Wk = (const float*)d_in[4];
  const float* bk = (const float*)d_in[5];
  // d_in[6] = vis_CA (unused)
  const int* flag = (const int*)d_in[7];  // same_WqWk
  float* out = (float*)d_out;

  char* ws = (char*)d_ws;
  bf16* Qp = (bf16*)ws;                          // 4 MiB: [32][1024][64] bf16
  bf16* Kp = (bf16*)(ws + (4u << 20));           // 4 MiB
  bf16* Wbh = (bf16*)(ws + (8u << 20));          // 64 KiB: [2][64][256] bf16
  bf16* Wbl = (bf16*)(ws + (8u << 20) + 65536);  // 64 KiB
  bf16* Vb = (bf16*)(ws + (9u << 20));           // 16 MiB: [32][256][1024] bf16

  prep_w_kernel<<<dim3(16, 2), 256, 0, stream>>>(Wq, Wk, flag, Wbh, Wbl);
  vconv_kernel<<<4096, 256, 0, stream>>>(kf, Vb);
  proj_kernel<<<dim3(8, 32, 2), 256, 0, stream>>>(qf, kf, Wbh, Wbl, bq, bk, flag, Qp, Kp);
  attn_kernel<<<dim3(16, 32), 256, 0, stream>>>(Vb, Qp, Kp, out);
}